// Round 1
// baseline (1750.998 us; speedup 1.0000x reference)
//
#include <hip/hip_runtime.h>
#include <stdint.h>

#define B_SZ 128
#define T_SZ 64
#define N_IN 1024
#define N_HID 4096
#define N_OUT 1024
#define TAU 0.9f
#define THRESH 0.5f
#define REC_SCALE 0.1f

// ---------------------------------------------------------------------------
// zero the persistent state region (h_mem, o_mem, spike masks) each call
// ---------------------------------------------------------------------------
__global__ void zero_state_kernel(float* p, int n) {
    int i = blockIdx.x * blockDim.x + threadIdx.x;
    int stride = gridDim.x * blockDim.x;
    for (; i < n; i += stride) p[i] = 0.0f;
}

// ---------------------------------------------------------------------------
// column sums of W_rec (4096 cols) and W_out (1024 cols), deterministic.
// block = 256 threads = 64 columns x 4 j-quarters, fixed-order reduce.
// grid = 80 blocks (64 for W_rec cols, 16 for W_out cols)
// ---------------------------------------------------------------------------
__global__ __launch_bounds__(256)
void colsum_kernel(const float* __restrict__ Wrec, const float* __restrict__ Wout,
                   float* __restrict__ cs_rec, float* __restrict__ cs_out) {
    __shared__ float part[4][64];
    int tid = threadIdx.x;
    int c = tid & 63, q = tid >> 6;
    int col = blockIdx.x * 64 + c;  // 0..5119
    float s = 0.f;
    if (col < N_HID) {
        const float* p = Wrec + col + (size_t)q * 1024 * N_HID;
        for (int j = 0; j < 1024; ++j) s += p[(size_t)j * N_HID];
    } else {
        int o = col - N_HID;
        const float* p = Wout + o + (size_t)q * 1024 * N_OUT;
        for (int j = 0; j < 1024; ++j) s += p[(size_t)j * N_OUT];
    }
    part[q][c] = s;
    __syncthreads();
    if (tid < 64) {
        float tot = part[0][tid] + part[1][tid] + part[2][tid] + part[3][tid];
        int col2 = blockIdx.x * 64 + tid;
        if (col2 < N_HID) cs_rec[col2] = tot;
        else              cs_out[col2 - N_HID] = tot;
    }
}

// ---------------------------------------------------------------------------
// fp32 tiled GEMM: inp_chunk[b*Tc+tl, h] = x[b, t0+tl, :] @ W_fc1[:, h]
// BM=BN=128, BK=16, 256 threads, 8x8 per thread.
// ---------------------------------------------------------------------------
#define BM 128
#define BN 128
#define BK 16

__global__ __launch_bounds__(256)
void fc1_gemm_kernel(const float* __restrict__ x, const float* __restrict__ W,
                     float* __restrict__ Cc, int t0, int Tc) {
    __shared__ float As[BK][BM];
    __shared__ float Bs[BK][BN];
    int tid = threadIdx.x;
    int bx = blockIdx.x;            // N tile (0..31)
    int by = blockIdx.y;            // M tile (0..Tc-1)
    int tx = tid & 15, ty = tid >> 4;
    int n_base = bx * BN;

    // hoisted A row pointers (2 float4 loads per K-tile per thread)
    const float* arow[2];
    int am[2], ak4[2];
    #pragma unroll
    for (int i = 0; i < 2; ++i) {
        int idx = tid + 256 * i;
        am[i] = idx >> 2;
        ak4[i] = (idx & 3) * 4;
        int mg = by * BM + am[i];           // row in chunk == b*Tc+tl
        int b = mg / Tc, tl = mg - b * Tc;
        arow[i] = x + (size_t)(b * T_SZ + t0 + tl) * N_IN + ak4[i];
    }
    // hoisted B pointers
    const float* brow[2];
    int bk[2], bn4[2];
    #pragma unroll
    for (int i = 0; i < 2; ++i) {
        int idx = tid + 256 * i;
        bk[i] = idx >> 5;
        bn4[i] = (idx & 31) * 4;
        brow[i] = W + (size_t)bk[i] * N_HID + n_base + bn4[i];
    }

    float acc[8][8] = {};
    for (int kt = 0; kt < N_IN; kt += BK) {
        #pragma unroll
        for (int i = 0; i < 2; ++i) {
            float4 v = *(const float4*)(arow[i] + kt);
            As[ak4[i] + 0][am[i]] = v.x;
            As[ak4[i] + 1][am[i]] = v.y;
            As[ak4[i] + 2][am[i]] = v.z;
            As[ak4[i] + 3][am[i]] = v.w;
        }
        #pragma unroll
        for (int i = 0; i < 2; ++i) {
            *(float4*)&Bs[bk[i]][bn4[i]] =
                *(const float4*)(brow[i] + (size_t)kt * N_HID);
        }
        __syncthreads();
        #pragma unroll
        for (int k = 0; k < BK; ++k) {
            float a[8], bb[8];
            *(float4*)&a[0]  = *(const float4*)&As[k][ty * 8];
            *(float4*)&a[4]  = *(const float4*)&As[k][ty * 8 + 4];
            *(float4*)&bb[0] = *(const float4*)&Bs[k][tx * 8];
            *(float4*)&bb[4] = *(const float4*)&Bs[k][tx * 8 + 4];
            #pragma unroll
            for (int i2 = 0; i2 < 8; ++i2)
                #pragma unroll
                for (int j2 = 0; j2 < 8; ++j2)
                    acc[i2][j2] += a[i2] * bb[j2];
        }
        __syncthreads();
    }
    #pragma unroll
    for (int i2 = 0; i2 < 8; ++i2) {
        int m = by * BM + ty * 8 + i2;
        float* crow = Cc + (size_t)m * N_HID + n_base + tx * 8;
        *(float4*)crow       = *(float4*)&acc[i2][0];
        *(float4*)(crow + 4) = *(float4*)&acc[i2][4];
    }
}

// ---------------------------------------------------------------------------
// min-side spike index list builder.
// Requires: mask up-to-date in LDS and a barrier BEFORE the call.
// Wave 0 builds list (ascending j) + publishes count & mode; trailing barrier.
// ---------------------------------------------------------------------------
__device__ __forceinline__ void build_list(unsigned long long* mask,
                                           unsigned short* list,
                                           int* sh_n, int* sh_inact,
                                           int lane, int wave) {
    if (wave == 0) {
        unsigned long long w = mask[lane];
        int cnt = __builtin_popcountll(w);
        int tot = cnt;
        #pragma unroll
        for (int d = 32; d > 0; d >>= 1) tot += __shfl_xor(tot, d, 64);
        int inact = tot > (N_HID / 2);
        unsigned long long wsel = inact ? ~w : w;
        int c = __builtin_popcountll(wsel);
        int scan = c;
        #pragma unroll
        for (int d = 1; d < 64; d <<= 1) {
            int v = __shfl_up(scan, d, 64);
            if (lane >= d) scan += v;
        }
        int off = scan - c;
        while (wsel) {
            int bpos = __builtin_ctzll(wsel);
            list[off++] = (unsigned short)(lane * 64 + bpos);
            wsel &= wsel - 1;
        }
        if (lane == 0) {
            *sh_n = inact ? (N_HID - tot) : tot;
            *sh_inact = inact;
        }
    }
    __syncthreads();
}

// ---------------------------------------------------------------------------
// Sequential RSNN step loop. One workgroup per batch element b.
// Thread t owns h = t + 256k (k=0..15) and o = t + 256k (k=0..3).
// Spike GEMMs done as min(active,inactive)-side row sums (+ colsum complement).
// ---------------------------------------------------------------------------
__global__ __launch_bounds__(256)
void rsnn_step_kernel(const float* __restrict__ inp,   // [B, Tc, N_HID]
                      const float* __restrict__ Wrec,  // [N_HID, N_HID]
                      const float* __restrict__ Wout,  // [N_HID, N_OUT]
                      const float* __restrict__ cs_rec,
                      const float* __restrict__ cs_out,
                      float* __restrict__ h_mem_g,     // [B, N_HID]
                      float* __restrict__ o_mem_g,     // [B, N_OUT]
                      unsigned long long* __restrict__ mask_g, // [B, 64]
                      float* __restrict__ out,         // [B, T, N_OUT]
                      int t0, int Tc) {
    __shared__ unsigned long long mask[64];
    __shared__ unsigned short list[N_HID];
    __shared__ int sh_n;
    __shared__ int sh_inact;

    const int b = blockIdx.x;
    const int t = threadIdx.x;
    const int lane = t & 63;
    const int wave = t >> 6;

    float hm[16], om[4], csr[16], cso[4];
    #pragma unroll
    for (int k = 0; k < 16; ++k) {
        hm[k]  = h_mem_g[(size_t)b * N_HID + t + 256 * k];
        csr[k] = cs_rec[t + 256 * k];
    }
    #pragma unroll
    for (int k = 0; k < 4; ++k) {
        om[k]  = o_mem_g[(size_t)b * N_OUT + t + 256 * k];
        cso[k] = cs_out[t + 256 * k];
    }
    if (t < 64) mask[t] = mask_g[b * 64 + t];
    __syncthreads();

    // previous-step spike flags for the hard reset term
    float spf[16];
    #pragma unroll
    for (int k = 0; k < 16; ++k) {
        int h = t + 256 * k;
        spf[k] = (float)((mask[h >> 6] >> (h & 63)) & 1ULL);
    }

    build_list(mask, list, &sh_n, &sh_inact, lane, wave);  // prev spikes

    for (int tl = 0; tl < Tc; ++tl) {
        // ---- recurrent row-sum over min side of previous spikes ----
        int n = sh_n, inact = sh_inact;
        float racc[16];
        #pragma unroll
        for (int k = 0; k < 16; ++k) racc[k] = 0.f;
        for (int i = 0; i < n; ++i) {
            int j = list[i];                       // LDS broadcast
            const float* row = Wrec + (size_t)j * N_HID + t;
            #pragma unroll
            for (int k = 0; k < 16; ++k) racc[k] += row[256 * k];
        }
        const float* inprow = inp + ((size_t)b * Tc + tl) * N_HID + t;
        bool snew[16];
        #pragma unroll
        for (int k = 0; k < 16; ++k) {
            float rec = REC_SCALE * (inact ? (csr[k] - racc[k]) : racc[k]);
            float v = TAU * hm[k] * (1.0f - spf[k]) + (inprow[256 * k] + rec);
            hm[k] = v;
            snew[k] = (v >= THRESH);
            spf[k] = snew[k] ? 1.0f : 0.0f;
        }
        __syncthreads();   // all list/mask readers done before overwrite
        // ---- publish new spikes: one ballot per k covers exactly one word ----
        #pragma unroll
        for (int k = 0; k < 16; ++k) {
            unsigned long long bal = __ballot(snew[k]);
            if (lane == 0) mask[wave + 4 * k] = bal;
        }
        __syncthreads();
        build_list(mask, list, &sh_n, &sh_inact, lane, wave);  // new spikes

        // ---- output row-sum over min side of NEW spikes ----
        n = sh_n; inact = sh_inact;
        float oacc[4] = {0.f, 0.f, 0.f, 0.f};
        for (int i = 0; i < n; ++i) {
            int j = list[i];
            const float* row = Wout + (size_t)j * N_OUT + t;
            #pragma unroll
            for (int k = 0; k < 4; ++k) oacc[k] += row[256 * k];
        }
        float* orow = out + ((size_t)b * T_SZ + (t0 + tl)) * N_OUT + t;
        #pragma unroll
        for (int k = 0; k < 4; ++k) {
            float contrib = inact ? (cso[k] - oacc[k]) : oacc[k];
            om[k] = TAU * om[k] + contrib;
            orow[256 * k] = om[k];
        }
        // list stays valid as "previous spikes" for the next iteration
    }

    // save state for next chunk
    #pragma unroll
    for (int k = 0; k < 16; ++k)
        h_mem_g[(size_t)b * N_HID + t + 256 * k] = hm[k];
    #pragma unroll
    for (int k = 0; k < 4; ++k)
        o_mem_g[(size_t)b * N_OUT + t + 256 * k] = om[k];
    __syncthreads();
    if (t < 64) mask_g[b * 64 + t] = mask[t];
}

// ---------------------------------------------------------------------------
extern "C" void kernel_launch(void* const* d_in, const int* in_sizes, int n_in,
                              void* d_out, int out_size, void* d_ws, size_t ws_size,
                              hipStream_t stream) {
    const float* x    = (const float*)d_in[0];
    const float* Wfc1 = (const float*)d_in[1];
    const float* Wrec = (const float*)d_in[2];
    const float* Wout = (const float*)d_in[3];
    float* out = (float*)d_out;

    // workspace layout
    float* h_mem = (float*)d_ws;                              // 128*4096 f32
    float* o_mem = h_mem + B_SZ * N_HID;                      // 128*1024 f32
    unsigned long long* maskg =
        (unsigned long long*)(o_mem + B_SZ * N_OUT);          // 128*64 u64
    float* cs_rec = (float*)(maskg + B_SZ * 64);              // 4096 f32
    float* cs_out = cs_rec + N_HID;                           // 1024 f32
    float* inp_chunk = cs_out + N_OUT;                        // 128*Tc*4096 f32

    size_t base_bytes = (size_t)(B_SZ * N_HID + B_SZ * N_OUT) * 4
                      + (size_t)B_SZ * 64 * 8
                      + (size_t)(N_HID + N_OUT) * 4;
    int Tc = 64;
    while (Tc > 1 && base_bytes + (size_t)B_SZ * Tc * N_HID * 4 > ws_size)
        Tc >>= 1;

    int state_floats = B_SZ * N_HID + B_SZ * N_OUT + B_SZ * 64 * 2;
    zero_state_kernel<<<256, 256, 0, stream>>>(h_mem, state_floats);
    colsum_kernel<<<80, 256, 0, stream>>>(Wrec, Wout, cs_rec, cs_out);

    for (int t0 = 0; t0 < T_SZ; t0 += Tc) {
        dim3 grid(N_HID / BN, Tc);
        fc1_gemm_kernel<<<grid, 256, 0, stream>>>(x, Wfc1, inp_chunk, t0, Tc);
        rsnn_step_kernel<<<B_SZ, 256, 0, stream>>>(inp_chunk, Wrec, Wout,
                                                   cs_rec, cs_out,
                                                   h_mem, o_mem, maskg, out,
                                                   t0, Tc);
    }
}

// Round 2
// 1535.394 us; speedup vs baseline: 1.1404x; 1.1404x over previous
//
#include <hip/hip_runtime.h>
#include <stdint.h>

#define B_SZ 128
#define T_SZ 64
#define N_IN 1024
#define N_HID 4096
#define N_OUT 1024
#define TAU 0.9f
#define THRESH 0.5f
#define REC_SCALE 0.1f

// ---------------------------------------------------------------------------
// zero the persistent state region (h_mem, o_mem, spike masks) each call
// ---------------------------------------------------------------------------
__global__ void zero_state_kernel(float* p, int n) {
    int i = blockIdx.x * blockDim.x + threadIdx.x;
    int stride = gridDim.x * blockDim.x;
    for (; i < n; i += stride) p[i] = 0.0f;
}

// ---------------------------------------------------------------------------
// column sums of W_rec (4096 cols) and W_out (1024 cols), deterministic.
// ---------------------------------------------------------------------------
__global__ __launch_bounds__(256)
void colsum_kernel(const float* __restrict__ Wrec, const float* __restrict__ Wout,
                   float* __restrict__ cs_rec, float* __restrict__ cs_out) {
    __shared__ float part[4][64];
    int tid = threadIdx.x;
    int c = tid & 63, q = tid >> 6;
    int col = blockIdx.x * 64 + c;  // 0..5119
    float s = 0.f;
    if (col < N_HID) {
        const float* p = Wrec + col + (size_t)q * 1024 * N_HID;
        for (int j = 0; j < 1024; ++j) s += p[(size_t)j * N_HID];
    } else {
        int o = col - N_HID;
        const float* p = Wout + o + (size_t)q * 1024 * N_OUT;
        for (int j = 0; j < 1024; ++j) s += p[(size_t)j * N_OUT];
    }
    part[q][c] = s;
    __syncthreads();
    if (tid < 64) {
        float tot = part[0][tid] + part[1][tid] + part[2][tid] + part[3][tid];
        int col2 = blockIdx.x * 64 + tid;
        if (col2 < N_HID) cs_rec[col2] = tot;
        else              cs_out[col2 - N_HID] = tot;
    }
}

// ---------------------------------------------------------------------------
// fp32 tiled GEMM: inp_chunk[b*Tc+tl, h] = x[b, t0+tl, :] @ W_fc1[:, h]
// ---------------------------------------------------------------------------
#define BM 128
#define BN 128
#define BK 16

__global__ __launch_bounds__(256)
void fc1_gemm_kernel(const float* __restrict__ x, const float* __restrict__ W,
                     float* __restrict__ Cc, int t0, int Tc) {
    __shared__ float As[BK][BM];
    __shared__ float Bs[BK][BN];
    int tid = threadIdx.x;
    int bx = blockIdx.x;            // N tile (0..31)
    int by = blockIdx.y;            // M tile (0..Tc-1)
    int tx = tid & 15, ty = tid >> 4;
    int n_base = bx * BN;

    const float* arow[2];
    int am[2], ak4[2];
    #pragma unroll
    for (int i = 0; i < 2; ++i) {
        int idx = tid + 256 * i;
        am[i] = idx >> 2;
        ak4[i] = (idx & 3) * 4;
        int mg = by * BM + am[i];           // row in chunk == b*Tc+tl
        int b = mg / Tc, tl = mg - b * Tc;
        arow[i] = x + (size_t)(b * T_SZ + t0 + tl) * N_IN + ak4[i];
    }
    const float* brow[2];
    int bk[2], bn4[2];
    #pragma unroll
    for (int i = 0; i < 2; ++i) {
        int idx = tid + 256 * i;
        bk[i] = idx >> 5;
        bn4[i] = (idx & 31) * 4;
        brow[i] = W + (size_t)bk[i] * N_HID + n_base + bn4[i];
    }

    float acc[8][8] = {};
    for (int kt = 0; kt < N_IN; kt += BK) {
        #pragma unroll
        for (int i = 0; i < 2; ++i) {
            float4 v = *(const float4*)(arow[i] + kt);
            As[ak4[i] + 0][am[i]] = v.x;
            As[ak4[i] + 1][am[i]] = v.y;
            As[ak4[i] + 2][am[i]] = v.z;
            As[ak4[i] + 3][am[i]] = v.w;
        }
        #pragma unroll
        for (int i = 0; i < 2; ++i) {
            *(float4*)&Bs[bk[i]][bn4[i]] =
                *(const float4*)(brow[i] + (size_t)kt * N_HID);
        }
        __syncthreads();
        #pragma unroll
        for (int k = 0; k < BK; ++k) {
            float a[8], bb[8];
            *(float4*)&a[0]  = *(const float4*)&As[k][ty * 8];
            *(float4*)&a[4]  = *(const float4*)&As[k][ty * 8 + 4];
            *(float4*)&bb[0] = *(const float4*)&Bs[k][tx * 8];
            *(float4*)&bb[4] = *(const float4*)&Bs[k][tx * 8 + 4];
            #pragma unroll
            for (int i2 = 0; i2 < 8; ++i2)
                #pragma unroll
                for (int j2 = 0; j2 < 8; ++j2)
                    acc[i2][j2] += a[i2] * bb[j2];
        }
        __syncthreads();
    }
    #pragma unroll
    for (int i2 = 0; i2 < 8; ++i2) {
        int m = by * BM + ty * 8 + i2;
        float* crow = Cc + (size_t)m * N_HID + n_base + tx * 8;
        *(float4*)crow       = *(float4*)&acc[i2][0];
        *(float4*)(crow + 4) = *(float4*)&acc[i2][4];
    }
}

// ---------------------------------------------------------------------------
// min-side spike index list builder (wave 0 only; barrier after).
// ---------------------------------------------------------------------------
__device__ __forceinline__ void build_list(unsigned long long* mask,
                                           unsigned short* list,
                                           int* sh_n, int* sh_inact,
                                           int lane, int wave) {
    if (wave == 0) {
        unsigned long long w = mask[lane];
        int cnt = __builtin_popcountll(w);
        int tot = cnt;
        #pragma unroll
        for (int d = 32; d > 0; d >>= 1) tot += __shfl_xor(tot, d, 64);
        int inact = tot > (N_HID / 2);
        unsigned long long wsel = inact ? ~w : w;
        int c = __builtin_popcountll(wsel);
        int scan = c;
        #pragma unroll
        for (int d = 1; d < 64; d <<= 1) {
            int v = __shfl_up(scan, d, 64);
            if (lane >= d) scan += v;
        }
        int off = scan - c;
        while (wsel) {
            int bpos = __builtin_ctzll(wsel);
            list[off++] = (unsigned short)(lane * 64 + bpos);
            wsel &= wsel - 1;
        }
        if (lane == 0) {
            *sh_n = inact ? (N_HID - tot) : tot;
            *sh_inact = inact;
        }
    }
    __syncthreads();
}

// ---------------------------------------------------------------------------
// Sequential RSNN step loop. One 1024-thread workgroup per batch element.
// Thread t owns h cols {t+1024k, k=0..3} and o col t.
// 4-row unrolled gathers w/ independent accumulators for MLP.
// ---------------------------------------------------------------------------
__global__ __launch_bounds__(1024, 1)
void rsnn_step_kernel(const float* __restrict__ inp,   // [B, Tc, N_HID]
                      const float* __restrict__ Wrec,  // [N_HID, N_HID]
                      const float* __restrict__ Wout,  // [N_HID, N_OUT]
                      const float* __restrict__ cs_rec,
                      const float* __restrict__ cs_out,
                      float* __restrict__ h_mem_g,     // [B, N_HID]
                      float* __restrict__ o_mem_g,     // [B, N_OUT]
                      unsigned long long* __restrict__ mask_g, // [B, 64]
                      float* __restrict__ out,         // [B, T, N_OUT]
                      int t0, int Tc) {
    __shared__ unsigned long long mask[64];
    __shared__ unsigned short list[N_HID];
    __shared__ int sh_n;
    __shared__ int sh_inact;

    const int b = blockIdx.x;
    const int t = threadIdx.x;           // 0..1023
    const int lane = t & 63;
    const int wave = t >> 6;             // 0..15

    float hm[4], csr[4], om, cso;
    #pragma unroll
    for (int k = 0; k < 4; ++k) {
        hm[k]  = h_mem_g[(size_t)b * N_HID + t + 1024 * k];
        csr[k] = cs_rec[t + 1024 * k];
    }
    om  = o_mem_g[(size_t)b * N_OUT + t];
    cso = cs_out[t];
    if (t < 64) mask[t] = mask_g[b * 64 + t];
    __syncthreads();

    // previous-step spike flags (hard reset term)
    float spf[4];
    #pragma unroll
    for (int k = 0; k < 4; ++k) {
        int h = t + 1024 * k;
        spf[k] = (float)((mask[h >> 6] >> (h & 63)) & 1ULL);
    }

    build_list(mask, list, &sh_n, &sh_inact, lane, wave);  // prev spikes

    for (int tl = 0; tl < Tc; ++tl) {
        // ---- recurrent gather over min side of previous spikes ----
        int n = sh_n, inact = sh_inact;
        float racc[4];
        {
            float a0[4] = {}, a1[4] = {}, a2[4] = {}, a3[4] = {};
            int i = 0;
            for (; i + 4 <= n; i += 4) {
                int j0 = list[i], j1 = list[i + 1];
                int j2 = list[i + 2], j3 = list[i + 3];
                const float* r0 = Wrec + (size_t)j0 * N_HID + t;
                const float* r1 = Wrec + (size_t)j1 * N_HID + t;
                const float* r2 = Wrec + (size_t)j2 * N_HID + t;
                const float* r3 = Wrec + (size_t)j3 * N_HID + t;
                #pragma unroll
                for (int k = 0; k < 4; ++k) {
                    a0[k] += r0[1024 * k];
                    a1[k] += r1[1024 * k];
                    a2[k] += r2[1024 * k];
                    a3[k] += r3[1024 * k];
                }
            }
            for (; i < n; ++i) {
                const float* r = Wrec + (size_t)list[i] * N_HID + t;
                #pragma unroll
                for (int k = 0; k < 4; ++k) a0[k] += r[1024 * k];
            }
            #pragma unroll
            for (int k = 0; k < 4; ++k)
                racc[k] = (a0[k] + a1[k]) + (a2[k] + a3[k]);
        }

        const float* inprow = inp + ((size_t)b * Tc + tl) * N_HID + t;
        bool snew[4];
        #pragma unroll
        for (int k = 0; k < 4; ++k) {
            float rec = REC_SCALE * (inact ? (csr[k] - racc[k]) : racc[k]);
            float v = TAU * hm[k] * (1.0f - spf[k]) + (inprow[1024 * k] + rec);
            hm[k] = v;
            snew[k] = (v >= THRESH);
            spf[k] = snew[k] ? 1.0f : 0.0f;
        }
        __syncthreads();   // all list/mask readers done before overwrite
        // publish new spikes: wave w, k -> mask word (w + 16k)
        #pragma unroll
        for (int k = 0; k < 4; ++k) {
            unsigned long long bal = __ballot(snew[k]);
            if (lane == 0) mask[wave + 16 * k] = bal;
        }
        __syncthreads();
        build_list(mask, list, &sh_n, &sh_inact, lane, wave);  // new spikes

        // ---- output gather over min side of NEW spikes ----
        n = sh_n; inact = sh_inact;
        float oacc;
        {
            float b0 = 0.f, b1 = 0.f, b2 = 0.f, b3 = 0.f;
            int i = 0;
            for (; i + 4 <= n; i += 4) {
                int j0 = list[i], j1 = list[i + 1];
                int j2 = list[i + 2], j3 = list[i + 3];
                b0 += Wout[(size_t)j0 * N_OUT + t];
                b1 += Wout[(size_t)j1 * N_OUT + t];
                b2 += Wout[(size_t)j2 * N_OUT + t];
                b3 += Wout[(size_t)j3 * N_OUT + t];
            }
            for (; i < n; ++i) b0 += Wout[(size_t)list[i] * N_OUT + t];
            oacc = (b0 + b1) + (b2 + b3);
        }
        float contrib = inact ? (cso - oacc) : oacc;
        om = TAU * om + contrib;
        out[((size_t)b * T_SZ + (t0 + tl)) * N_OUT + t] = om;
        // list stays valid as "previous spikes" for the next iteration
    }

    // save state for next chunk
    #pragma unroll
    for (int k = 0; k < 4; ++k)
        h_mem_g[(size_t)b * N_HID + t + 1024 * k] = hm[k];
    o_mem_g[(size_t)b * N_OUT + t] = om;
    __syncthreads();
    if (t < 64) mask_g[b * 64 + t] = mask[t];
}

// ---------------------------------------------------------------------------
extern "C" void kernel_launch(void* const* d_in, const int* in_sizes, int n_in,
                              void* d_out, int out_size, void* d_ws, size_t ws_size,
                              hipStream_t stream) {
    const float* x    = (const float*)d_in[0];
    const float* Wfc1 = (const float*)d_in[1];
    const float* Wrec = (const float*)d_in[2];
    const float* Wout = (const float*)d_in[3];
    float* out = (float*)d_out;

    // workspace layout
    float* h_mem = (float*)d_ws;                              // 128*4096 f32
    float* o_mem = h_mem + B_SZ * N_HID;                      // 128*1024 f32
    unsigned long long* maskg =
        (unsigned long long*)(o_mem + B_SZ * N_OUT);          // 128*64 u64
    float* cs_rec = (float*)(maskg + B_SZ * 64);              // 4096 f32
    float* cs_out = cs_rec + N_HID;                           // 1024 f32
    float* inp_chunk = cs_out + N_OUT;                        // 128*Tc*4096 f32

    size_t base_bytes = (size_t)(B_SZ * N_HID + B_SZ * N_OUT) * 4
                      + (size_t)B_SZ * 64 * 8
                      + (size_t)(N_HID + N_OUT) * 4;
    int Tc = 64;
    while (Tc > 1 && base_bytes + (size_t)B_SZ * Tc * N_HID * 4 > ws_size)
        Tc >>= 1;

    int state_floats = B_SZ * N_HID + B_SZ * N_OUT + B_SZ * 64 * 2;
    zero_state_kernel<<<256, 256, 0, stream>>>(h_mem, state_floats);
    colsum_kernel<<<80, 256, 0, stream>>>(Wrec, Wout, cs_rec, cs_out);

    for (int t0 = 0; t0 < T_SZ; t0 += Tc) {
        dim3 grid(N_HID / BN, Tc);
        fc1_gemm_kernel<<<grid, 256, 0, stream>>>(x, Wfc1, inp_chunk, t0, Tc);
        rsnn_step_kernel<<<B_SZ, 1024, 0, stream>>>(inp_chunk, Wrec, Wout,
                                                    cs_rec, cs_out,
                                                    h_mem, o_mem, maskg, out,
                                                    t0, Tc);
    }
}

// Round 3
// 1098.152 us; speedup vs baseline: 1.5945x; 1.3982x over previous
//
#include <hip/hip_runtime.h>
#include <stdint.h>

#define B_SZ 128
#define T_SZ 64
#define N_IN 1024
#define N_HID 4096
#define N_OUT 1024
#define TAU 0.9f
#define THRESH 0.5f
#define REC_SCALE 0.1f

typedef __attribute__((ext_vector_type(8))) short sh8;
typedef __attribute__((ext_vector_type(4))) float f32x4;
typedef __attribute__((ext_vector_type(4))) unsigned short ush4;

// ---------------------------------------------------------------------------
// helpers
// ---------------------------------------------------------------------------
__device__ __forceinline__ unsigned short f2bf_rn(float f) {
    unsigned u = __float_as_uint(f);
    unsigned r = (u + 0x7FFFu + ((u >> 16) & 1u)) >> 16;
    return (unsigned short)r;
}
__device__ __forceinline__ float bf2f(unsigned short h) {
    return __uint_as_float((unsigned)h << 16);
}
__device__ __forceinline__ void gload_lds16(const void* g, void* l) {
    __builtin_amdgcn_global_load_lds(
        (const __attribute__((address_space(1))) void*)g,
        (__attribute__((address_space(3))) void*)l, 16, 0, 0);
}

// ---------------------------------------------------------------------------
__global__ void zero_state_kernel(float* p, int n) {
    int i = blockIdx.x * blockDim.x + threadIdx.x;
    int stride = gridDim.x * blockDim.x;
    for (; i < n; i += stride) p[i] = 0.0f;
}

// ---------------------------------------------------------------------------
// column sums of W_rec / W_out (fp32, must match rsnn's fp32 gather exactly)
// ---------------------------------------------------------------------------
__global__ __launch_bounds__(256)
void colsum_kernel(const float* __restrict__ Wrec, const float* __restrict__ Wout,
                   float* __restrict__ cs_rec, float* __restrict__ cs_out) {
    __shared__ float part[4][64];
    int tid = threadIdx.x;
    int c = tid & 63, q = tid >> 6;
    int col = blockIdx.x * 64 + c;  // 0..5119
    float s = 0.f;
    if (col < N_HID) {
        const float* p = Wrec + col + (size_t)q * 1024 * N_HID;
        for (int j = 0; j < 1024; ++j) s += p[(size_t)j * N_HID];
    } else {
        int o = col - N_HID;
        const float* p = Wout + o + (size_t)q * 1024 * N_OUT;
        for (int j = 0; j < 1024; ++j) s += p[(size_t)j * N_OUT];
    }
    part[q][c] = s;
    __syncthreads();
    if (tid < 64) {
        float tot = part[0][tid] + part[1][tid] + part[2][tid] + part[3][tid];
        int col2 = blockIdx.x * 64 + tid;
        if (col2 < N_HID) cs_rec[col2] = tot;
        else              cs_out[col2 - N_HID] = tot;
    }
}

// ---------------------------------------------------------------------------
// x [B,T,1024] fp32 -> Ax [128*Tc][2048] bf16  (cols 0..1023 hi, 1024..2047 lo)
// ---------------------------------------------------------------------------
__global__ __launch_bounds__(256)
void convert_x_kernel(const float* __restrict__ x, unsigned short* __restrict__ Ax,
                      int t0, int Tc) {
    int total4 = B_SZ * Tc * (N_IN / 4);
    int i = blockIdx.x * blockDim.x + threadIdx.x;
    int stride = gridDim.x * blockDim.x;
    for (; i < total4; i += stride) {
        int m = i >> 8;              // / 256 float4 per row
        int c4 = i & 255;
        int b = m / Tc, tl = m - b * Tc;
        float4 v = *(const float4*)(x + ((size_t)(b * T_SZ + t0 + tl) * N_IN) + c4 * 4);
        ush4 hi, lo;
        float f[4] = {v.x, v.y, v.z, v.w};
        #pragma unroll
        for (int j = 0; j < 4; ++j) {
            unsigned short h = f2bf_rn(f[j]);
            hi[j] = h;
            lo[j] = f2bf_rn(f[j] - bf2f(h));
        }
        unsigned short* row = Ax + (size_t)m * 2048;
        *(ush4*)(row + c4 * 4)        = hi;
        *(ush4*)(row + 1024 + c4 * 4) = lo;
    }
}

// ---------------------------------------------------------------------------
// W_fc1 [1024][4096] fp32 -> Bt [4096][2048] bf16, transposed:
//   Bt[n][k] = hi(W[k][n]), Bt[n][1024+k] = lo(W[k][n])
// tile: 32(k) x 64(n), LDS transpose with +1 pad
// ---------------------------------------------------------------------------
__global__ __launch_bounds__(256)
void convert_w_kernel(const float* __restrict__ W, unsigned short* __restrict__ Bt) {
    __shared__ float ts[32][65];
    int tid = threadIdx.x;
    int k0 = blockIdx.x * 32;     // 0..992
    int n0 = blockIdx.y * 64;     // 0..4032
    #pragma unroll
    for (int rr = 0; rr < 8; ++rr) {
        int kl = (tid >> 6) * 8 + rr;        // 0..31
        int nl = tid & 63;
        ts[kl][nl] = W[(size_t)(k0 + kl) * N_HID + n0 + nl];
    }
    __syncthreads();
    #pragma unroll
    for (int rr = 0; rr < 8; ++rr) {
        int nl = (tid >> 5) + rr * 8;        // 0..63
        int kl = tid & 31;
        float v = ts[kl][nl];
        unsigned short h = f2bf_rn(v);
        unsigned short l = f2bf_rn(v - bf2f(h));
        unsigned short* row = Bt + (size_t)(n0 + nl) * 2048;
        row[k0 + kl]        = h;
        row[1024 + k0 + kl] = l;
    }
}

// ---------------------------------------------------------------------------
// MFMA NT-GEMM, K'=3072 virtual (bf16x3):
//   kk in [0,1024):    x_hi @ W_hi
//   kk in [1024,2048): x_lo @ W_hi
//   kk in [2048,3072): x_hi @ W_lo
// A [M][2048] (x_hi|x_lo), Bt [4096][2048] (W_hi|W_lo), C [M][4096] fp32.
// m97 structure: 128x128 tile, BK=32, 4 waves @ 4x4 16x16x32 acc,
// global_load_lds width-16, 2-barrier K-loop.
// ---------------------------------------------------------------------------
__global__ __launch_bounds__(256)
void fc1_mfma_kernel(const unsigned short* __restrict__ A,
                     const unsigned short* __restrict__ Bt,
                     float* __restrict__ C) {
    __shared__ __attribute__((aligned(16))) unsigned short As[128 * 32];
    __shared__ __attribute__((aligned(16))) unsigned short Bs[128 * 32];
    const int tid = threadIdx.x;
    const int lane = tid & 63;
    const int wave = tid >> 6;
    const int wm = (wave >> 1) * 64;
    const int wn = (wave & 1) * 64;
    const int quad = lane >> 4, l16 = lane & 15;
    const int m0 = blockIdx.y * 128, n0 = blockIdx.x * 128;

    const unsigned short* aptr[2];
    const unsigned short* bptr[2];
    unsigned short* alds[2];
    unsigned short* blds[2];
    #pragma unroll
    for (int i = 0; i < 2; ++i) {
        int idx = tid + 256 * i;
        int row = idx >> 2, cg = idx & 3;
        aptr[i] = A  + (size_t)(m0 + row) * 2048 + cg * 8;
        bptr[i] = Bt + (size_t)(n0 + row) * 2048 + cg * 8;
        alds[i] = As + idx * 8;
        blds[i] = Bs + idx * 8;
    }

    f32x4 acc[4][4] = {};
    for (int kt = 0; kt < 96; ++kt) {
        int kk = kt * 32;
        int ak = (kk < 2048) ? kk : kk - 2048;
        int bk = (kk < 1024) ? kk : kk - 1024;
        __syncthreads();                     // LDS free to overwrite
        #pragma unroll
        for (int i = 0; i < 2; ++i) {
            gload_lds16(aptr[i] + ak, alds[i]);
            gload_lds16(bptr[i] + bk, blds[i]);
        }
        __syncthreads();                     // drain vmcnt + barrier
        sh8 af[4], bf[4];
        #pragma unroll
        for (int mt = 0; mt < 4; ++mt)
            af[mt] = *(const sh8*)&As[(wm + mt * 16 + l16) * 32 + quad * 8];
        #pragma unroll
        for (int nt = 0; nt < 4; ++nt)
            bf[nt] = *(const sh8*)&Bs[(wn + nt * 16 + l16) * 32 + quad * 8];
        #pragma unroll
        for (int mt = 0; mt < 4; ++mt)
            #pragma unroll
            for (int nt = 0; nt < 4; ++nt)
                acc[mt][nt] = __builtin_amdgcn_mfma_f32_16x16x32_bf16(
                    af[mt], bf[nt], acc[mt][nt], 0, 0, 0);
    }
    #pragma unroll
    for (int mt = 0; mt < 4; ++mt)
        #pragma unroll
        for (int nt = 0; nt < 4; ++nt) {
            int col = n0 + wn + nt * 16 + l16;
            #pragma unroll
            for (int r = 0; r < 4; ++r) {
                int m = m0 + wm + mt * 16 + quad * 4 + r;
                C[(size_t)m * N_HID + col] = acc[mt][nt][r];
            }
        }
}

// ---------------------------------------------------------------------------
// min-side spike index list builder (wave 0 only; barrier after).
// ---------------------------------------------------------------------------
__device__ __forceinline__ void build_list(unsigned long long* mask,
                                           unsigned short* list,
                                           int* sh_n, int* sh_inact,
                                           int lane, int wave) {
    if (wave == 0) {
        unsigned long long w = mask[lane];
        int cnt = __builtin_popcountll(w);
        int tot = cnt;
        #pragma unroll
        for (int d = 32; d > 0; d >>= 1) tot += __shfl_xor(tot, d, 64);
        int inact = tot > (N_HID / 2);
        unsigned long long wsel = inact ? ~w : w;
        int c = __builtin_popcountll(wsel);
        int scan = c;
        #pragma unroll
        for (int d = 1; d < 64; d <<= 1) {
            int v = __shfl_up(scan, d, 64);
            if (lane >= d) scan += v;
        }
        int off = scan - c;
        while (wsel) {
            int bpos = __builtin_ctzll(wsel);
            list[off++] = (unsigned short)(lane * 64 + bpos);
            wsel &= wsel - 1;
        }
        if (lane == 0) {
            *sh_n = inact ? (N_HID - tot) : tot;
            *sh_inact = inact;
        }
    }
    __syncthreads();
}

// ---------------------------------------------------------------------------
// Sequential RSNN step loop. One 1024-thread workgroup per batch element.
// ---------------------------------------------------------------------------
__global__ __launch_bounds__(1024, 1)
void rsnn_step_kernel(const float* __restrict__ inp,   // [B, Tc, N_HID]
                      const float* __restrict__ Wrec,  // [N_HID, N_HID]
                      const float* __restrict__ Wout,  // [N_HID, N_OUT]
                      const float* __restrict__ cs_rec,
                      const float* __restrict__ cs_out,
                      float* __restrict__ h_mem_g,
                      float* __restrict__ o_mem_g,
                      unsigned long long* __restrict__ mask_g,
                      float* __restrict__ out,
                      int t0, int Tc) {
    __shared__ unsigned long long mask[64];
    __shared__ unsigned short list[N_HID];
    __shared__ int sh_n;
    __shared__ int sh_inact;

    const int b = blockIdx.x;
    const int t = threadIdx.x;           // 0..1023
    const int lane = t & 63;
    const int wave = t >> 6;             // 0..15

    float hm[4], csr[4], om, cso;
    #pragma unroll
    for (int k = 0; k < 4; ++k) {
        hm[k]  = h_mem_g[(size_t)b * N_HID + t + 1024 * k];
        csr[k] = cs_rec[t + 1024 * k];
    }
    om  = o_mem_g[(size_t)b * N_OUT + t];
    cso = cs_out[t];
    if (t < 64) mask[t] = mask_g[b * 64 + t];
    __syncthreads();

    float spf[4];
    #pragma unroll
    for (int k = 0; k < 4; ++k) {
        int h = t + 1024 * k;
        spf[k] = (float)((mask[h >> 6] >> (h & 63)) & 1ULL);
    }

    build_list(mask, list, &sh_n, &sh_inact, lane, wave);  // prev spikes

    for (int tl = 0; tl < Tc; ++tl) {
        int n = sh_n, inact = sh_inact;
        float racc[4];
        {
            float a0[4] = {}, a1[4] = {}, a2[4] = {}, a3[4] = {};
            int i = 0;
            for (; i + 4 <= n; i += 4) {
                int j0 = list[i], j1 = list[i + 1];
                int j2 = list[i + 2], j3 = list[i + 3];
                const float* r0 = Wrec + (size_t)j0 * N_HID + t;
                const float* r1 = Wrec + (size_t)j1 * N_HID + t;
                const float* r2 = Wrec + (size_t)j2 * N_HID + t;
                const float* r3 = Wrec + (size_t)j3 * N_HID + t;
                #pragma unroll
                for (int k = 0; k < 4; ++k) {
                    a0[k] += r0[1024 * k];
                    a1[k] += r1[1024 * k];
                    a2[k] += r2[1024 * k];
                    a3[k] += r3[1024 * k];
                }
            }
            for (; i < n; ++i) {
                const float* r = Wrec + (size_t)list[i] * N_HID + t;
                #pragma unroll
                for (int k = 0; k < 4; ++k) a0[k] += r[1024 * k];
            }
            #pragma unroll
            for (int k = 0; k < 4; ++k)
                racc[k] = (a0[k] + a1[k]) + (a2[k] + a3[k]);
        }

        const float* inprow = inp + ((size_t)b * Tc + tl) * N_HID + t;
        bool snew[4];
        #pragma unroll
        for (int k = 0; k < 4; ++k) {
            float rec = REC_SCALE * (inact ? (csr[k] - racc[k]) : racc[k]);
            float v = TAU * hm[k] * (1.0f - spf[k]) + (inprow[1024 * k] + rec);
            hm[k] = v;
            snew[k] = (v >= THRESH);
            spf[k] = snew[k] ? 1.0f : 0.0f;
        }
        __syncthreads();
        #pragma unroll
        for (int k = 0; k < 4; ++k) {
            unsigned long long bal = __ballot(snew[k]);
            if (lane == 0) mask[wave + 16 * k] = bal;
        }
        __syncthreads();
        build_list(mask, list, &sh_n, &sh_inact, lane, wave);  // new spikes

        n = sh_n; inact = sh_inact;
        float oacc;
        {
            float b0 = 0.f, b1 = 0.f, b2 = 0.f, b3 = 0.f;
            int i = 0;
            for (; i + 4 <= n; i += 4) {
                int j0 = list[i], j1 = list[i + 1];
                int j2 = list[i + 2], j3 = list[i + 3];
                b0 += Wout[(size_t)j0 * N_OUT + t];
                b1 += Wout[(size_t)j1 * N_OUT + t];
                b2 += Wout[(size_t)j2 * N_OUT + t];
                b3 += Wout[(size_t)j3 * N_OUT + t];
            }
            for (; i < n; ++i) b0 += Wout[(size_t)list[i] * N_OUT + t];
            oacc = (b0 + b1) + (b2 + b3);
        }
        float contrib = inact ? (cso - oacc) : oacc;
        om = TAU * om + contrib;
        out[((size_t)b * T_SZ + (t0 + tl)) * N_OUT + t] = om;
    }

    #pragma unroll
    for (int k = 0; k < 4; ++k)
        h_mem_g[(size_t)b * N_HID + t + 1024 * k] = hm[k];
    o_mem_g[(size_t)b * N_OUT + t] = om;
    __syncthreads();
    if (t < 64) mask_g[b * 64 + t] = mask[t];
}

// ---------------------------------------------------------------------------
extern "C" void kernel_launch(void* const* d_in, const int* in_sizes, int n_in,
                              void* d_out, int out_size, void* d_ws, size_t ws_size,
                              hipStream_t stream) {
    const float* x    = (const float*)d_in[0];
    const float* Wfc1 = (const float*)d_in[1];
    const float* Wrec = (const float*)d_in[2];
    const float* Wout = (const float*)d_in[3];
    float* out = (float*)d_out;

    // workspace layout (all 16B-aligned)
    float* h_mem = (float*)d_ws;                               // 2 MB
    float* o_mem = h_mem + B_SZ * N_HID;                       // 0.5 MB
    unsigned long long* maskg =
        (unsigned long long*)(o_mem + B_SZ * N_OUT);           // 64 KB
    float* cs_rec = (float*)(maskg + B_SZ * 64);               // 16 KB
    float* cs_out = cs_rec + N_HID;                            // 4 KB
    unsigned short* Bt = (unsigned short*)(cs_out + N_OUT);    // 16.78 MB
    unsigned short* Ax = Bt + (size_t)N_HID * 2048;            // Tc*0.5 MB
    // inp_chunk follows Ax (depends on Tc)

    size_t fixed_bytes = (size_t)(B_SZ * N_HID + B_SZ * N_OUT) * 4
                       + (size_t)B_SZ * 64 * 8
                       + (size_t)(N_HID + N_OUT) * 4
                       + (size_t)N_HID * 2048 * 2;
    int Tc = 64;
    while (Tc > 1 &&
           fixed_bytes + (size_t)Tc * (B_SZ * 2048 * 2 + B_SZ * N_HID * 4) > ws_size)
        Tc >>= 1;
    float* inp_chunk = (float*)(Ax + (size_t)B_SZ * Tc * 2048);

    int state_floats = B_SZ * N_HID + B_SZ * N_OUT + B_SZ * 64 * 2;
    zero_state_kernel<<<256, 256, 0, stream>>>(h_mem, state_floats);
    colsum_kernel<<<80, 256, 0, stream>>>(Wrec, Wout, cs_rec, cs_out);
    convert_w_kernel<<<dim3(32, 64), 256, 0, stream>>>(Wfc1, Bt);

    for (int t0 = 0; t0 < T_SZ; t0 += Tc) {
        convert_x_kernel<<<2048, 256, 0, stream>>>(x, Ax, t0, Tc);
        fc1_mfma_kernel<<<dim3(N_HID / 128, Tc), 256, 0, stream>>>(Ax, Bt, inp_chunk);
        rsnn_step_kernel<<<B_SZ, 1024, 0, stream>>>(inp_chunk, Wrec, Wout,
                                                    cs_rec, cs_out,
                                                    h_mem, o_mem, maskg, out,
                                                    t0, Tc);
    }
}

// Round 4
// 937.665 us; speedup vs baseline: 1.8674x; 1.1712x over previous
//
#include <hip/hip_runtime.h>
#include <stdint.h>

#define B_SZ 128
#define T_SZ 64
#define N_IN 1024
#define N_HID 4096
#define N_OUT 1024
#define TAU 0.9f
#define THRESH 0.5f
#define REC_SCALE 0.1f

typedef __attribute__((ext_vector_type(8))) short sh8;
typedef __attribute__((ext_vector_type(4))) float f32x4;
typedef __attribute__((ext_vector_type(4))) unsigned short ush4;

// ---------------------------------------------------------------------------
// helpers
// ---------------------------------------------------------------------------
__device__ __forceinline__ unsigned short f2bf_rn(float f) {
    unsigned u = __float_as_uint(f);
    unsigned r = (u + 0x7FFFu + ((u >> 16) & 1u)) >> 16;
    return (unsigned short)r;
}
__device__ __forceinline__ float bf2f(unsigned short h) {
    return __uint_as_float((unsigned)h << 16);
}
__device__ __forceinline__ void gload_lds16(const void* g, void* l) {
    __builtin_amdgcn_global_load_lds(
        (const __attribute__((address_space(1))) void*)g,
        (__attribute__((address_space(3))) void*)l, 16, 0, 0);
}
// compress low nibbles of 4 bytes into 16 bits
__device__ __forceinline__ unsigned pack4(unsigned a) {
    a &= 0x0F0F0F0Fu;
    a = (a | (a >> 4)) & 0x00FF00FFu;
    a = (a | (a >> 8)) & 0x0000FFFFu;
    return a;
}

// ---------------------------------------------------------------------------
__global__ void zero_state_kernel(float* p, int n) {
    int i = blockIdx.x * blockDim.x + threadIdx.x;
    int stride = gridDim.x * blockDim.x;
    for (; i < n; i += stride) p[i] = 0.0f;
}

// ---------------------------------------------------------------------------
// fp32 -> bf16 (round-to-nearest-even), vectorized x4
// ---------------------------------------------------------------------------
__global__ __launch_bounds__(256)
void f32_to_bf16_kernel(const float* __restrict__ src,
                        unsigned short* __restrict__ dst, int n4) {
    int i = blockIdx.x * blockDim.x + threadIdx.x;
    int stride = gridDim.x * blockDim.x;
    for (; i < n4; i += stride) {
        float4 v = ((const float4*)src)[i];
        ush4 o;
        o[0] = f2bf_rn(v.x); o[1] = f2bf_rn(v.y);
        o[2] = f2bf_rn(v.z); o[3] = f2bf_rn(v.w);
        ((ush4*)dst)[i] = o;
    }
}

// ---------------------------------------------------------------------------
// column sums of the bf16-rounded W_rec / W_out (fp32 accumulation, fixed
// order matching the gather's complement identity up to fp32 assoc noise)
// ---------------------------------------------------------------------------
__global__ __launch_bounds__(256)
void colsum_bf16_kernel(const unsigned short* __restrict__ WrecB,
                        const unsigned short* __restrict__ WoutB,
                        float* __restrict__ cs_rec, float* __restrict__ cs_out) {
    __shared__ float part[4][64];
    int tid = threadIdx.x;
    int c = tid & 63, q = tid >> 6;
    int col = blockIdx.x * 64 + c;  // 0..5119
    float s = 0.f;
    if (col < N_HID) {
        const unsigned short* p = WrecB + col + (size_t)q * 1024 * N_HID;
        for (int j = 0; j < 1024; ++j) s += bf2f(p[(size_t)j * N_HID]);
    } else {
        int o = col - N_HID;
        const unsigned short* p = WoutB + o + (size_t)q * 1024 * N_OUT;
        for (int j = 0; j < 1024; ++j) s += bf2f(p[(size_t)j * N_OUT]);
    }
    part[q][c] = s;
    __syncthreads();
    if (tid < 64) {
        float tot = part[0][tid] + part[1][tid] + part[2][tid] + part[3][tid];
        int col2 = blockIdx.x * 64 + tid;
        if (col2 < N_HID) cs_rec[col2] = tot;
        else              cs_out[col2 - N_HID] = tot;
    }
}

// ---------------------------------------------------------------------------
// x [B,T,1024] fp32 -> Ax [128*Tc][2048] bf16  (cols 0..1023 hi, 1024..2047 lo)
// ---------------------------------------------------------------------------
__global__ __launch_bounds__(256)
void convert_x_kernel(const float* __restrict__ x, unsigned short* __restrict__ Ax,
                      int t0, int Tc) {
    int total4 = B_SZ * Tc * (N_IN / 4);
    int i = blockIdx.x * blockDim.x + threadIdx.x;
    int stride = gridDim.x * blockDim.x;
    for (; i < total4; i += stride) {
        int m = i >> 8;              // / 256 float4 per row
        int c4 = i & 255;
        int b = m / Tc, tl = m - b * Tc;
        float4 v = *(const float4*)(x + ((size_t)(b * T_SZ + t0 + tl) * N_IN) + c4 * 4);
        ush4 hi, lo;
        float f[4] = {v.x, v.y, v.z, v.w};
        #pragma unroll
        for (int j = 0; j < 4; ++j) {
            unsigned short h = f2bf_rn(f[j]);
            hi[j] = h;
            lo[j] = f2bf_rn(f[j] - bf2f(h));
        }
        unsigned short* row = Ax + (size_t)m * 2048;
        *(ush4*)(row + c4 * 4)        = hi;
        *(ush4*)(row + 1024 + c4 * 4) = lo;
    }
}

// ---------------------------------------------------------------------------
// W_fc1 [1024][4096] fp32 -> Bt [4096][2048] bf16, transposed (hi|lo)
// ---------------------------------------------------------------------------
__global__ __launch_bounds__(256)
void convert_w_kernel(const float* __restrict__ W, unsigned short* __restrict__ Bt) {
    __shared__ float ts[32][65];
    int tid = threadIdx.x;
    int k0 = blockIdx.x * 32;     // 0..992
    int n0 = blockIdx.y * 64;     // 0..4032
    #pragma unroll
    for (int rr = 0; rr < 8; ++rr) {
        int kl = (tid >> 6) * 8 + rr;        // 0..31
        int nl = tid & 63;
        ts[kl][nl] = W[(size_t)(k0 + kl) * N_HID + n0 + nl];
    }
    __syncthreads();
    #pragma unroll
    for (int rr = 0; rr < 8; ++rr) {
        int nl = (tid >> 5) + rr * 8;        // 0..63
        int kl = tid & 31;
        float v = ts[kl][nl];
        unsigned short h = f2bf_rn(v);
        unsigned short l = f2bf_rn(v - bf2f(h));
        unsigned short* row = Bt + (size_t)(n0 + nl) * 2048;
        row[k0 + kl]        = h;
        row[1024 + k0 + kl] = l;
    }
}

// ---------------------------------------------------------------------------
// MFMA NT-GEMM, K'=3072 virtual (bf16x3): see round-3 notes. Unchanged.
// ---------------------------------------------------------------------------
__global__ __launch_bounds__(256)
void fc1_mfma_kernel(const unsigned short* __restrict__ A,
                     const unsigned short* __restrict__ Bt,
                     float* __restrict__ C) {
    __shared__ __attribute__((aligned(16))) unsigned short As[128 * 32];
    __shared__ __attribute__((aligned(16))) unsigned short Bs[128 * 32];
    const int tid = threadIdx.x;
    const int lane = tid & 63;
    const int wave = tid >> 6;
    const int wm = (wave >> 1) * 64;
    const int wn = (wave & 1) * 64;
    const int quad = lane >> 4, l16 = lane & 15;
    const int m0 = blockIdx.y * 128, n0 = blockIdx.x * 128;

    const unsigned short* aptr[2];
    const unsigned short* bptr[2];
    unsigned short* alds[2];
    unsigned short* blds[2];
    #pragma unroll
    for (int i = 0; i < 2; ++i) {
        int idx = tid + 256 * i;
        int row = idx >> 2, cg = idx & 3;
        aptr[i] = A  + (size_t)(m0 + row) * 2048 + cg * 8;
        bptr[i] = Bt + (size_t)(n0 + row) * 2048 + cg * 8;
        alds[i] = As + idx * 8;
        blds[i] = Bs + idx * 8;
    }

    f32x4 acc[4][4] = {};
    for (int kt = 0; kt < 96; ++kt) {
        int kk = kt * 32;
        int ak = (kk < 2048) ? kk : kk - 2048;
        int bk = (kk < 1024) ? kk : kk - 1024;
        __syncthreads();
        #pragma unroll
        for (int i = 0; i < 2; ++i) {
            gload_lds16(aptr[i] + ak, alds[i]);
            gload_lds16(bptr[i] + bk, blds[i]);
        }
        __syncthreads();
        sh8 af[4], bf[4];
        #pragma unroll
        for (int mt = 0; mt < 4; ++mt)
            af[mt] = *(const sh8*)&As[(wm + mt * 16 + l16) * 32 + quad * 8];
        #pragma unroll
        for (int nt = 0; nt < 4; ++nt)
            bf[nt] = *(const sh8*)&Bs[(wn + nt * 16 + l16) * 32 + quad * 8];
        #pragma unroll
        for (int mt = 0; mt < 4; ++mt)
            #pragma unroll
            for (int nt = 0; nt < 4; ++nt)
                acc[mt][nt] = __builtin_amdgcn_mfma_f32_16x16x32_bf16(
                    af[mt], bf[nt], acc[mt][nt], 0, 0, 0);
    }
    #pragma unroll
    for (int mt = 0; mt < 4; ++mt)
        #pragma unroll
        for (int nt = 0; nt < 4; ++nt) {
            int col = n0 + wn + nt * 16 + l16;
            #pragma unroll
            for (int r = 0; r < 4; ++r) {
                int m = m0 + wm + mt * 16 + quad * 4 + r;
                C[(size_t)m * N_HID + col] = acc[mt][nt][r];
            }
        }
}

// ---------------------------------------------------------------------------
// min-side list build from a 64-bit word per lane (wave 0 only).
// ---------------------------------------------------------------------------
__device__ __forceinline__ void build_list_core(unsigned long long w,
                                                unsigned short* list,
                                                int* sh_n, int* sh_inact,
                                                int lane) {
    int tot = __builtin_popcountll(w);
    #pragma unroll
    for (int d = 32; d > 0; d >>= 1) tot += __shfl_xor(tot, d, 64);
    int inact = tot > (N_HID / 2);
    unsigned long long wsel = inact ? ~w : w;
    int c = __builtin_popcountll(wsel);
    int scan = c;
    #pragma unroll
    for (int d = 1; d < 64; d <<= 1) {
        int v = __shfl_up(scan, d, 64);
        if (lane >= d) scan += v;
    }
    int off = scan - c;
    while (wsel) {
        int bpos = __builtin_ctzll(wsel);
        list[off++] = (unsigned short)(lane * 64 + bpos);
        wsel &= wsel - 1;
    }
    if (lane == 0) {
        *sh_n = inact ? (N_HID - tot) : tot;
        *sh_inact = inact;
    }
}

// ---------------------------------------------------------------------------
// Sequential RSNN step loop. One 1024-thread workgroup per batch element.
// Thread t owns hidden cols 4t..4t+3 (one dwordx2 bf16 load per gathered row)
// and out col t (one ushort load per row). bf16 weight copies; colsums are
// over the SAME bf16 values so the complement identity stays consistent.
// ---------------------------------------------------------------------------
__global__ __launch_bounds__(1024, 4)
void rsnn_step_kernel(const float* __restrict__ inp,            // [B, Tc, N_HID]
                      const unsigned short* __restrict__ WrecB, // [N_HID][N_HID] bf16
                      const unsigned short* __restrict__ WoutB, // [N_HID][N_OUT] bf16
                      const float* __restrict__ cs_rec,
                      const float* __restrict__ cs_out,
                      float* __restrict__ h_mem_g,
                      float* __restrict__ o_mem_g,
                      unsigned long long* __restrict__ mask_g,
                      float* __restrict__ out,
                      int t0, int Tc) {
    __shared__ unsigned long long mask[64];
    __shared__ unsigned short list[N_HID];
    __shared__ __attribute__((aligned(16))) unsigned char spk[1024];
    __shared__ int sh_n;
    __shared__ int sh_inact;

    const int b = blockIdx.x;
    const int t = threadIdx.x;           // 0..1023
    const int lane = t & 63;
    const int wave = t >> 6;

    float hm[4], csr[4];
    #pragma unroll
    for (int k = 0; k < 4; ++k) {
        hm[k]  = h_mem_g[(size_t)b * N_HID + 4 * t + k];
        csr[k] = cs_rec[4 * t + k];
    }
    float om  = o_mem_g[(size_t)b * N_OUT + t];
    float cso = cs_out[t];
    if (t < 64) mask[t] = mask_g[b * 64 + t];
    __syncthreads();

    // previous-step spike flags for cols 4t..4t+3 (hard reset term)
    float spf[4];
    {
        unsigned long long w = mask[t >> 4];
        int sh = 4 * (t & 15);
        #pragma unroll
        for (int k = 0; k < 4; ++k)
            spf[k] = (float)((w >> (sh + k)) & 1ULL);
    }
    if (wave == 0) build_list_core(mask[lane], list, &sh_n, &sh_inact, lane);
    __syncthreads();

    const unsigned short* Wb = WrecB + 4 * t;
    const unsigned short* Wo = WoutB + t;

    for (int tl = 0; tl < Tc; ++tl) {
        // ---- recurrent gather over min side of previous spikes ----
        int n = sh_n, inact = sh_inact;
        float a[8][4] = {};
        int i = 0;
        for (; i + 8 <= n; i += 8) {
            int j[8];
            #pragma unroll
            for (int r = 0; r < 8; ++r) j[r] = list[i + r];
            #pragma unroll
            for (int r = 0; r < 8; ++r) {
                uint2 v = *(const uint2*)(Wb + (size_t)j[r] * N_HID);
                a[r][0] += __uint_as_float(v.x << 16);
                a[r][1] += __uint_as_float(v.x & 0xFFFF0000u);
                a[r][2] += __uint_as_float(v.y << 16);
                a[r][3] += __uint_as_float(v.y & 0xFFFF0000u);
            }
        }
        for (; i < n; ++i) {
            uint2 v = *(const uint2*)(Wb + (size_t)list[i] * N_HID);
            a[0][0] += __uint_as_float(v.x << 16);
            a[0][1] += __uint_as_float(v.x & 0xFFFF0000u);
            a[0][2] += __uint_as_float(v.y << 16);
            a[0][3] += __uint_as_float(v.y & 0xFFFF0000u);
        }
        float racc[4];
        #pragma unroll
        for (int k = 0; k < 4; ++k)
            racc[k] = ((a[0][k] + a[1][k]) + (a[2][k] + a[3][k]))
                    + ((a[4][k] + a[5][k]) + (a[6][k] + a[7][k]));

        float4 iv = *(const float4*)(inp + ((size_t)b * Tc + tl) * N_HID + 4 * t);
        float ivv[4] = {iv.x, iv.y, iv.z, iv.w};
        unsigned nib = 0;
        #pragma unroll
        for (int k = 0; k < 4; ++k) {
            float rec = REC_SCALE * (inact ? (csr[k] - racc[k]) : racc[k]);
            float v = TAU * hm[k] * (1.0f - spf[k]) + (ivv[k] + rec);
            hm[k] = v;
            bool s = (v >= THRESH);
            spf[k] = s ? 1.0f : 0.0f;
            nib |= (s ? 1u : 0u) << k;
        }
        __syncthreads();            // all list readers done before overwrite
        spk[t] = (unsigned char)nib;
        __syncthreads();            // spk visible to wave 0
        if (wave == 0) {
            uint4 q = *(const uint4*)&spk[lane * 16];
            unsigned w0 = pack4(q.x) | (pack4(q.y) << 16);
            unsigned w1 = pack4(q.z) | (pack4(q.w) << 16);
            unsigned long long w = (unsigned long long)w0
                                 | ((unsigned long long)w1 << 32);
            mask[lane] = w;
            build_list_core(w, list, &sh_n, &sh_inact, lane);
        }
        __syncthreads();            // list/counts ready

        // ---- output gather over min side of NEW spikes ----
        n = sh_n; inact = sh_inact;
        float o8[8] = {};
        i = 0;
        for (; i + 8 <= n; i += 8) {
            int j[8];
            #pragma unroll
            for (int r = 0; r < 8; ++r) j[r] = list[i + r];
            #pragma unroll
            for (int r = 0; r < 8; ++r)
                o8[r] += bf2f(Wo[(size_t)j[r] * N_OUT]);
        }
        for (; i < n; ++i) o8[0] += bf2f(Wo[(size_t)list[i] * N_OUT]);
        float oacc = ((o8[0] + o8[1]) + (o8[2] + o8[3]))
                   + ((o8[4] + o8[5]) + (o8[6] + o8[7]));
        float contrib = inact ? (cso - oacc) : oacc;
        om = TAU * om + contrib;
        out[((size_t)b * T_SZ + (t0 + tl)) * N_OUT + t] = om;
        // list stays valid as "previous spikes" for the next iteration
    }

    #pragma unroll
    for (int k = 0; k < 4; ++k)
        h_mem_g[(size_t)b * N_HID + 4 * t + k] = hm[k];
    o_mem_g[(size_t)b * N_OUT + t] = om;
    __syncthreads();
    if (t < 64) mask_g[b * 64 + t] = mask[t];
}

// ---------------------------------------------------------------------------
extern "C" void kernel_launch(void* const* d_in, const int* in_sizes, int n_in,
                              void* d_out, int out_size, void* d_ws, size_t ws_size,
                              hipStream_t stream) {
    const float* x    = (const float*)d_in[0];
    const float* Wfc1 = (const float*)d_in[1];
    const float* Wrec = (const float*)d_in[2];
    const float* Wout = (const float*)d_in[3];
    float* out = (float*)d_out;

    // workspace layout (all 16B-aligned)
    float* h_mem = (float*)d_ws;                               // 2 MB
    float* o_mem = h_mem + B_SZ * N_HID;                       // 0.5 MB
    unsigned long long* maskg =
        (unsigned long long*)(o_mem + B_SZ * N_OUT);           // 64 KB
    float* cs_rec = (float*)(maskg + B_SZ * 64);               // 16 KB
    float* cs_out = cs_rec + N_HID;                            // 4 KB
    unsigned short* WrecB = (unsigned short*)(cs_out + N_OUT); // 33.55 MB
    unsigned short* WoutB = WrecB + (size_t)N_HID * N_HID;     // 8.39 MB
    unsigned short* Bt    = WoutB + (size_t)N_HID * N_OUT;     // 16.78 MB
    unsigned short* Ax    = Bt + (size_t)N_HID * 2048;         // Tc-dep
    // inp_chunk follows Ax

    size_t fixed_bytes = (size_t)(B_SZ * N_HID + B_SZ * N_OUT) * 4
                       + (size_t)B_SZ * 64 * 8
                       + (size_t)(N_HID + N_OUT) * 4
                       + (size_t)N_HID * N_HID * 2
                       + (size_t)N_HID * N_OUT * 2
                       + (size_t)N_HID * 2048 * 2;
    int Tc = 64;
    while (Tc > 1 &&
           fixed_bytes + (size_t)Tc * (B_SZ * 2048 * 2 + B_SZ * N_HID * 4) > ws_size)
        Tc >>= 1;
    float* inp_chunk = (float*)(Ax + (size_t)B_SZ * Tc * 2048);

    int state_floats = B_SZ * N_HID + B_SZ * N_OUT + B_SZ * 64 * 2;
    zero_state_kernel<<<256, 256, 0, stream>>>(h_mem, state_floats);
    f32_to_bf16_kernel<<<2048, 256, 0, stream>>>(Wrec, WrecB, N_HID * N_HID / 4);
    f32_to_bf16_kernel<<<1024, 256, 0, stream>>>(Wout, WoutB, N_HID * N_OUT / 4);
    colsum_bf16_kernel<<<80, 256, 0, stream>>>(WrecB, WoutB, cs_rec, cs_out);
    convert_w_kernel<<<dim3(32, 64), 256, 0, stream>>>(Wfc1, Bt);

    for (int t0 = 0; t0 < T_SZ; t0 += Tc) {
        convert_x_kernel<<<2048, 256, 0, stream>>>(x, Ax, t0, Tc);
        fc1_mfma_kernel<<<dim3(N_HID / 128, Tc), 256, 0, stream>>>(Ax, Bt, inp_chunk);
        rsnn_step_kernel<<<B_SZ, 1024, 0, stream>>>(inp_chunk, WrecB, WoutB,
                                                    cs_rec, cs_out,
                                                    h_mem, o_mem, maskg, out,
                                                    t0, Tc);
    }
}